// Round 1
// baseline (757.431 us; speedup 1.0000x reference)
//
#include <hip/hip_runtime.h>
#include <stdint.h>

#define C_IN 64
#define C_OUT 128
#define NBUCK 65536

typedef unsigned int u32;
typedef unsigned long long u64;

// ---------- K1: compute compressed keys + bucket histogram ----------
__global__ void k1_keys(const int* __restrict__ grid, const int* __restrict__ batch,
                        const int* __restrict__ stride, int n,
                        u32* __restrict__ keys, u32* __restrict__ hist) {
  int i = blockIdx.x * blockDim.x + threadIdx.x;
  if (i >= n) return;
  int s = stride[0];
  u32 gx = (u32)(grid[3 * i] / s);
  u32 gy = (u32)(grid[3 * i + 1] / s);
  u32 gz = (u32)(grid[3 * i + 2] / s);
  u32 b = (u32)batch[i];
  u32 key = (b << 30) | (gz << 20) | (gy << 10) | gx;
  keys[i] = key;
  atomicAdd(&hist[key >> 16], 1u);
}

// ---------- K2: exclusive scan of 65536 bucket counts (1 block) ----------
__global__ void k2_scan(const u32* __restrict__ hist, u32* __restrict__ off,
                        u32* __restrict__ cursor) {
  __shared__ u32 part[1024];
  int t = threadIdx.x;
  u32 s = 0;
  for (int k = 0; k < 64; k++) s += hist[t * 64 + k];
  part[t] = s;
  __syncthreads();
  for (int d = 1; d < 1024; d <<= 1) {
    u32 v = (t >= d) ? part[t - d] : 0u;
    __syncthreads();
    part[t] += v;
    __syncthreads();
  }
  u32 run = part[t] - s;  // exclusive base for this thread's 64 buckets
  for (int k = 0; k < 64; k++) {
    u32 h = hist[t * 64 + k];
    off[t * 64 + k] = run;
    cursor[t * 64 + k] = run;
    run += h;
  }
  if (t == 1023) off[NBUCK] = run;  // == n
}

// ---------- K3: scatter (key,idx) pairs into buckets ----------
__global__ void k3_scatter(const u32* __restrict__ keys, u32* __restrict__ cursor,
                           u64* __restrict__ pairs, int n) {
  int i = blockIdx.x * blockDim.x + threadIdx.x;
  if (i >= n) return;
  u32 key = keys[i];
  u32 pos = atomicAdd(&cursor[key >> 16], 1u);
  pairs[pos] = ((u64)key << 32) | (u32)i;
}

// ---------- K4: per-bucket insertion sort (full u64 compare => deterministic) ----------
__global__ void k4_sort(u64* __restrict__ pairs, const u32* __restrict__ off) {
  int b = blockIdx.x * blockDim.x + threadIdx.x;
  if (b >= NBUCK) return;
  u32 lo = off[b], hi = off[b + 1];
  for (u32 i = lo + 1; i < hi; i++) {
    u64 v = pairs[i];
    u32 j = i;
    while (j > lo && pairs[j - 1] > v) { pairs[j] = pairs[j - 1]; j--; }
    pairs[j] = v;
  }
}

// ---------- K5a: per-block head counts (4096 positions/block) ----------
__global__ void k5a_count(const u64* __restrict__ pairs, int n, u32* __restrict__ blockCnt) {
  __shared__ u32 part[256];
  int tid = threadIdx.x;
  int p0 = blockIdx.x * 4096 + tid * 16;
  u32 cnt = 0;
  u32 prevkey = (p0 > 0 && p0 < n) ? (u32)(pairs[p0 - 1] >> 32) : 0u;
  for (int r = 0; r < 16; r++) {
    int p = p0 + r;
    if (p >= n) break;
    u32 k = (u32)(pairs[p] >> 32);
    cnt += (p == 0) || (k != prevkey);
    prevkey = k;
  }
  part[tid] = cnt;
  __syncthreads();
  for (int d = 128; d > 0; d >>= 1) {
    if (tid < d) part[tid] += part[tid + d];
    __syncthreads();
  }
  if (tid == 0) blockCnt[blockIdx.x] = part[0];
}

// ---------- K5b: scan block head counts (1 block, nb<=256) ----------
__global__ void k5b_scanblocks(const u32* __restrict__ blockCnt, int nb,
                               u32* __restrict__ blockBase, u32* __restrict__ meta,
                               u32* __restrict__ segStart, int n) {
  __shared__ u32 part[256];
  int t = threadIdx.x;
  u32 v = (t < nb) ? blockCnt[t] : 0u;
  part[t] = v;
  __syncthreads();
  for (int d = 1; d < 256; d <<= 1) {
    u32 x = (t >= d) ? part[t - d] : 0u;
    __syncthreads();
    part[t] += x;
    __syncthreads();
  }
  if (t < nb) blockBase[t] = part[t] - v;
  if (t == 255) {
    u32 total = part[255];
    meta[0] = total;           // number of unique segments
    segStart[total] = (u32)n;  // sentinel
  }
}

// ---------- K5c: assign ranks, write cluster ids (+multi flag), seg starts, grid/batch ----------
__global__ void k5c_assign(const u64* __restrict__ pairs, int n,
                           const u32* __restrict__ blockBase,
                           u32* __restrict__ segStart, u32* __restrict__ cluster,
                           float* __restrict__ out_grid, float* __restrict__ out_batch) {
  __shared__ u32 part[256];
  int tid = threadIdx.x;
  int p0 = blockIdx.x * 4096 + tid * 16;
  u32 cnt = 0;
  u32 prevkey = (p0 > 0 && p0 < n) ? (u32)(pairs[p0 - 1] >> 32) : 0u;
  for (int r = 0; r < 16; r++) {
    int p = p0 + r;
    if (p >= n) break;
    u32 k = (u32)(pairs[p] >> 32);
    cnt += (p == 0) || (k != prevkey);
    prevkey = k;
  }
  part[tid] = cnt;
  __syncthreads();
  for (int d = 1; d < 256; d <<= 1) {
    u32 x = (tid >= d) ? part[tid - d] : 0u;
    __syncthreads();
    part[tid] += x;
    __syncthreads();
  }
  u32 heads = blockBase[blockIdx.x] + part[tid] - cnt;
  prevkey = (p0 > 0 && p0 < n) ? (u32)(pairs[p0 - 1] >> 32) : 0u;
  for (int r = 0; r < 16; r++) {
    int p = p0 + r;
    if (p >= n) break;
    u64 cur = pairs[p];
    u32 k = (u32)(cur >> 32);
    bool head = (p == 0) || (k != prevkey);
    if (head) {
      segStart[heads] = (u32)p;
      out_grid[(size_t)heads * 3 + 0] = (float)(k & 0x3FFu);
      out_grid[(size_t)heads * 3 + 1] = (float)((k >> 10) & 0x3FFu);
      out_grid[(size_t)heads * 3 + 2] = (float)((k >> 20) & 0x3FFu);
      out_batch[heads] = (float)(k >> 30);
      heads++;
    }
    u32 seg = heads - 1;
    bool next_eq = (p + 1 < n) && ((u32)(pairs[p + 1] >> 32) == k);
    bool prev_eq = (p > 0) && (prevkey == k);
    u32 multi = (next_eq || prev_eq) ? 0x80000000u : 0u;
    cluster[(u32)(cur & 0xFFFFFFFFu)] = seg | multi;
    prevkey = k;
  }
}

// ---------- K6: fused GEMM + scatter store for singleton clusters ----------
__global__ __launch_bounds__(256) void k6_gemm(
    const float* __restrict__ feat, const float* __restrict__ weight,
    const float* __restrict__ bias, const u32* __restrict__ cluster,
    float* __restrict__ out_feat, int n) {
  __shared__ float ldsF[32 * C_IN];
  __shared__ u32 ldsC[32];
  const int tid = threadIdx.x;
  const int lane = tid & 63;
  const int wid = tid >> 6;
  const int h = wid & 1;
  const int c = h * 64 + lane;  // output channel owned by this thread
  float wreg[C_IN];
  const float4* wrow = (const float4*)(weight + (size_t)c * C_IN);
#pragma unroll
  for (int q = 0; q < 16; q++) {
    float4 v = wrow[q];
    wreg[4 * q] = v.x; wreg[4 * q + 1] = v.y; wreg[4 * q + 2] = v.z; wreg[4 * q + 3] = v.w;
  }
  const float bc = bias[c];
  const int nch = (n + 31) >> 5;
  for (int ch = blockIdx.x; ch < nch; ch += gridDim.x) {
    const int base = ch << 5;
    __syncthreads();  // protect LDS from previous iteration readers
    if (base + 32 <= n) {
      const float4* src = (const float4*)(feat + (size_t)base * C_IN);
      ((float4*)ldsF)[tid] = src[tid];
      ((float4*)ldsF)[tid + 256] = src[tid + 256];
    } else {
      for (int t = tid; t < 32 * C_IN; t += 256) {
        int p = base + (t >> 6);
        ldsF[t] = (p < n) ? feat[(size_t)p * C_IN + (t & 63)] : 0.f;
      }
    }
    if (tid < 32) ldsC[tid] = (base + tid < n) ? cluster[base + tid] : 0x80000000u;
    __syncthreads();
    for (int j = (wid >> 1); j < 32; j += 2) {
      if (base + j >= n) break;
      u32 cl = ldsC[j];
      if (cl & 0x80000000u) continue;  // multi-point cluster: handled in finalize
      const float4* f4 = (const float4*)(ldsF + j * C_IN);
      float acc = bc;
#pragma unroll
      for (int q = 0; q < 16; q++) {
        float4 v = f4[q];
        acc = fmaf(v.x, wreg[4 * q], acc);
        acc = fmaf(v.y, wreg[4 * q + 1], acc);
        acc = fmaf(v.z, wreg[4 * q + 2], acc);
        acc = fmaf(v.w, wreg[4 * q + 3], acc);
      }
      out_feat[(size_t)cl * C_OUT + c] = acc;
    }
  }
}

// ---------- K7: counts, coord means, invalid zeros, multi-cluster rows ----------
__global__ void k7_finalize(const u64* __restrict__ pairs, const u32* __restrict__ segStart,
                            const u32* __restrict__ meta, const float* __restrict__ coord,
                            const float* __restrict__ feat, const float* __restrict__ weight,
                            const float* __restrict__ bias, float* __restrict__ out_feat,
                            float* __restrict__ out_coord, float* __restrict__ out_grid,
                            float* __restrict__ out_batch, float* __restrict__ out_counts,
                            int n) {
  int t = blockIdx.x * blockDim.x + threadIdx.x;
  if (t >= n) return;
  u32 numSeg = meta[0];
  if ((u32)t < numSeg) {
    u32 st = segStart[t], en = segStart[t + 1];
    u32 cnt = en - st;
    out_counts[t] = (float)cnt;
    float sx = 0.f, sy = 0.f, sz = 0.f;
    for (u32 e = st; e < en; e++) {
      u32 idx = (u32)(pairs[e] & 0xFFFFFFFFu);
      sx += coord[(size_t)idx * 3 + 0];
      sy += coord[(size_t)idx * 3 + 1];
      sz += coord[(size_t)idx * 3 + 2];
    }
    float fc = (float)cnt;
    out_coord[(size_t)t * 3 + 0] = sx / fc;
    out_coord[(size_t)t * 3 + 1] = sy / fc;
    out_coord[(size_t)t * 3 + 2] = sz / fc;
    if (cnt > 1) {  // rare: exact matmul + max over members
      for (int c = 0; c < C_OUT; c++) {
        float m = -3.4e38f;
        for (u32 e = st; e < en; e++) {
          u32 idx = (u32)(pairs[e] & 0xFFFFFFFFu);
          float d = bias[c];
          for (int k = 0; k < C_IN; k++)
            d = fmaf(feat[(size_t)idx * C_IN + k], weight[(size_t)c * C_IN + k], d);
          m = fmaxf(m, d);
        }
        out_feat[(size_t)t * C_OUT + c] = m;
      }
    }
  } else {
    out_counts[t] = 0.f;
    out_batch[t] = 0.f;
    out_coord[(size_t)t * 3 + 0] = 0.f;
    out_coord[(size_t)t * 3 + 1] = 0.f;
    out_coord[(size_t)t * 3 + 2] = 0.f;
    out_grid[(size_t)t * 3 + 0] = 0.f;
    out_grid[(size_t)t * 3 + 1] = 0.f;
    out_grid[(size_t)t * 3 + 2] = 0.f;
    for (int c = 0; c < C_OUT; c++) out_feat[(size_t)t * C_OUT + c] = 0.f;
  }
}

extern "C" void kernel_launch(void* const* d_in, const int* in_sizes, int n_in,
                              void* d_out, int out_size, void* d_ws, size_t ws_size,
                              hipStream_t stream) {
  const float* feat = (const float*)d_in[0];
  const float* coord = (const float*)d_in[1];
  const float* weight = (const float*)d_in[2];
  const float* bias = (const float*)d_in[3];
  const int* grid = (const int*)d_in[4];
  const int* batch = (const int*)d_in[5];
  const int* stride = (const int*)d_in[6];
  const int n = in_sizes[0] / C_IN;

  float* out_feat = (float*)d_out;
  float* out_coord = out_feat + (size_t)n * C_OUT;
  float* out_grid = out_coord + (size_t)n * 3;
  float* out_batch = out_grid + (size_t)n * 3;
  float* out_counts = out_batch + n;

  u32* W = (u32*)d_ws;
  u32* hist = W;                   // 65536
  u32* cursor = W + 65536;         // 65536
  u32* off = W + 131072;           // 65537
  u32* meta = W + 196864;          // [0] = numSeg
  u32* blockCnt = W + 196992;      // up to 2048
  u32* blockBase = W + 199040;     // up to 2048
  u32* keys = W + 262144;          // n
  u32* cluster = keys + n;         // n
  u32* segStart = cluster + n;     // n+1
  size_t pe = 262144 + 3 * (size_t)n + 2;
  pe &= ~(size_t)1;                // 8-byte align for u64
  u64* pairs = (u64*)(W + pe);     // n

  hipMemsetAsync(hist, 0, NBUCK * sizeof(u32), stream);
  int nb = (n + 255) / 256;
  k1_keys<<<nb, 256, 0, stream>>>(grid, batch, stride, n, keys, hist);
  k2_scan<<<1, 1024, 0, stream>>>(hist, off, cursor);
  k3_scatter<<<nb, 256, 0, stream>>>(keys, cursor, pairs, n);
  k4_sort<<<NBUCK / 256, 256, 0, stream>>>(pairs, off);
  int nb5 = (n + 4095) / 4096;
  k5a_count<<<nb5, 256, 0, stream>>>(pairs, n, blockCnt);
  k5b_scanblocks<<<1, 256, 0, stream>>>(blockCnt, nb5, blockBase, meta, segStart, n);
  k5c_assign<<<nb5, 256, 0, stream>>>(pairs, n, blockBase, segStart, cluster, out_grid, out_batch);
  k6_gemm<<<2048, 256, 0, stream>>>(feat, weight, bias, cluster, out_feat, n);
  k7_finalize<<<nb, 256, 0, stream>>>(pairs, segStart, meta, coord, feat, weight, bias,
                                      out_feat, out_coord, out_grid, out_batch, out_counts, n);
}

// Round 2
// 526.234 us; speedup vs baseline: 1.4393x; 1.4393x over previous
//
#include <hip/hip_runtime.h>
#include <stdint.h>

#define C_IN 64
#define C_OUT 128
#define NBUCK 65536

typedef unsigned int u32;
typedef unsigned long long u64;

// ---------- K1: compute compressed keys + bucket histogram ----------
__global__ void k1_keys(const int* __restrict__ grid, const int* __restrict__ batch,
                        const int* __restrict__ stride, int n,
                        u32* __restrict__ keys, u32* __restrict__ hist) {
  int i = blockIdx.x * blockDim.x + threadIdx.x;
  if (i >= n) return;
  int s = stride[0];
  u32 gx = (u32)(grid[3 * i] / s);
  u32 gy = (u32)(grid[3 * i + 1] / s);
  u32 gz = (u32)(grid[3 * i + 2] / s);
  u32 b = (u32)batch[i];
  u32 key = (b << 30) | (gz << 20) | (gy << 10) | gx;
  keys[i] = key;
  atomicAdd(&hist[key >> 16], 1u);
}

// ---------- K2: exclusive scan of 65536 bucket counts (1 block) ----------
__global__ void k2_scan(const u32* __restrict__ hist, u32* __restrict__ off,
                        u32* __restrict__ cursor) {
  __shared__ u32 part[1024];
  int t = threadIdx.x;
  u32 s = 0;
  for (int k = 0; k < 64; k++) s += hist[t * 64 + k];
  part[t] = s;
  __syncthreads();
  for (int d = 1; d < 1024; d <<= 1) {
    u32 v = (t >= d) ? part[t - d] : 0u;
    __syncthreads();
    part[t] += v;
    __syncthreads();
  }
  u32 run = part[t] - s;  // exclusive base for this thread's 64 buckets
  for (int k = 0; k < 64; k++) {
    u32 h = hist[t * 64 + k];
    off[t * 64 + k] = run;
    cursor[t * 64 + k] = run;
    run += h;
  }
  if (t == 1023) off[NBUCK] = run;  // == n
}

// ---------- K3: scatter (key,idx) pairs into buckets ----------
__global__ void k3_scatter(const u32* __restrict__ keys, u32* __restrict__ cursor,
                           u64* __restrict__ pairs, int n) {
  int i = blockIdx.x * blockDim.x + threadIdx.x;
  if (i >= n) return;
  u32 key = keys[i];
  u32 pos = atomicAdd(&cursor[key >> 16], 1u);
  pairs[pos] = ((u64)key << 32) | (u32)i;
}

// ---------- K4: per-bucket insertion sort (full u64 compare => deterministic) ----------
__global__ void k4_sort(u64* __restrict__ pairs, const u32* __restrict__ off) {
  int b = blockIdx.x * blockDim.x + threadIdx.x;
  if (b >= NBUCK) return;
  u32 lo = off[b], hi = off[b + 1];
  for (u32 i = lo + 1; i < hi; i++) {
    u64 v = pairs[i];
    u32 j = i;
    while (j > lo && pairs[j - 1] > v) { pairs[j] = pairs[j - 1]; j--; }
    pairs[j] = v;
  }
}

// ---------- K5a: per-block head counts (4096 positions/block) ----------
__global__ void k5a_count(const u64* __restrict__ pairs, int n, u32* __restrict__ blockCnt) {
  __shared__ u32 part[256];
  int tid = threadIdx.x;
  int p0 = blockIdx.x * 4096 + tid * 16;
  u32 cnt = 0;
  u32 prevkey = (p0 > 0 && p0 < n) ? (u32)(pairs[p0 - 1] >> 32) : 0u;
  for (int r = 0; r < 16; r++) {
    int p = p0 + r;
    if (p >= n) break;
    u32 k = (u32)(pairs[p] >> 32);
    cnt += (p == 0) || (k != prevkey);
    prevkey = k;
  }
  part[tid] = cnt;
  __syncthreads();
  for (int d = 128; d > 0; d >>= 1) {
    if (tid < d) part[tid] += part[tid + d];
    __syncthreads();
  }
  if (tid == 0) blockCnt[blockIdx.x] = part[0];
}

// ---------- K5b: scan block head counts (1 block, nb<=256) ----------
__global__ void k5b_scanblocks(const u32* __restrict__ blockCnt, int nb,
                               u32* __restrict__ blockBase, u32* __restrict__ meta,
                               u32* __restrict__ segStart, int n) {
  __shared__ u32 part[256];
  int t = threadIdx.x;
  u32 v = (t < nb) ? blockCnt[t] : 0u;
  part[t] = v;
  __syncthreads();
  for (int d = 1; d < 256; d <<= 1) {
    u32 x = (t >= d) ? part[t - d] : 0u;
    __syncthreads();
    part[t] += x;
    __syncthreads();
  }
  if (t < nb) blockBase[t] = part[t] - v;
  if (t == 254) meta[1] = 0u;  // reset multi-cluster counter (runs before k5c)
  if (t == 255) {
    u32 total = part[255];
    meta[0] = total;           // number of unique segments
    segStart[total] = (u32)n;  // sentinel
  }
}

// ---------- K5c: assign ranks, write cluster ids (+multi flag), seg starts, grid/batch ----------
__global__ void k5c_assign(const u64* __restrict__ pairs, int n,
                           const u32* __restrict__ blockBase,
                           u32* __restrict__ segStart, u32* __restrict__ cluster,
                           float* __restrict__ out_grid, float* __restrict__ out_batch,
                           u32* __restrict__ meta, u32* __restrict__ multiList) {
  __shared__ u32 part[256];
  int tid = threadIdx.x;
  int p0 = blockIdx.x * 4096 + tid * 16;
  u32 cnt = 0;
  u32 prevkey = (p0 > 0 && p0 < n) ? (u32)(pairs[p0 - 1] >> 32) : 0u;
  for (int r = 0; r < 16; r++) {
    int p = p0 + r;
    if (p >= n) break;
    u32 k = (u32)(pairs[p] >> 32);
    cnt += (p == 0) || (k != prevkey);
    prevkey = k;
  }
  part[tid] = cnt;
  __syncthreads();
  for (int d = 1; d < 256; d <<= 1) {
    u32 x = (tid >= d) ? part[tid - d] : 0u;
    __syncthreads();
    part[tid] += x;
    __syncthreads();
  }
  u32 heads = blockBase[blockIdx.x] + part[tid] - cnt;
  prevkey = (p0 > 0 && p0 < n) ? (u32)(pairs[p0 - 1] >> 32) : 0u;
  for (int r = 0; r < 16; r++) {
    int p = p0 + r;
    if (p >= n) break;
    u64 cur = pairs[p];
    u32 k = (u32)(cur >> 32);
    bool head = (p == 0) || (k != prevkey);
    bool next_eq = (p + 1 < n) && ((u32)(pairs[p + 1] >> 32) == k);
    if (head) {
      segStart[heads] = (u32)p;
      out_grid[(size_t)heads * 3 + 0] = (float)(k & 0x3FFu);
      out_grid[(size_t)heads * 3 + 1] = (float)((k >> 10) & 0x3FFu);
      out_grid[(size_t)heads * 3 + 2] = (float)((k >> 20) & 0x3FFu);
      out_batch[heads] = (float)(k >> 30);
      heads++;
      if (next_eq) {  // multi-point cluster: record seg id for k8
        u32 slot = atomicAdd(&meta[1], 1u);
        multiList[slot] = heads - 1;
      }
    }
    u32 seg = heads - 1;
    bool prev_eq = (p > 0) && (prevkey == k);
    u32 multi = (next_eq || prev_eq) ? 0x80000000u : 0u;
    cluster[(u32)(cur & 0xFFFFFFFFu)] = seg | multi;
    prevkey = k;
  }
}

// ---------- K6: fused GEMM + scatter store for singleton clusters ----------
__global__ __launch_bounds__(256) void k6_gemm(
    const float* __restrict__ feat, const float* __restrict__ weight,
    const float* __restrict__ bias, const u32* __restrict__ cluster,
    float* __restrict__ out_feat, int n) {
  __shared__ float ldsF[32 * C_IN];
  __shared__ u32 ldsC[32];
  const int tid = threadIdx.x;
  const int lane = tid & 63;
  const int wid = tid >> 6;
  const int h = wid & 1;
  const int c = h * 64 + lane;  // output channel owned by this thread
  float wreg[C_IN];
  const float4* wrow = (const float4*)(weight + (size_t)c * C_IN);
#pragma unroll
  for (int q = 0; q < 16; q++) {
    float4 v = wrow[q];
    wreg[4 * q] = v.x; wreg[4 * q + 1] = v.y; wreg[4 * q + 2] = v.z; wreg[4 * q + 3] = v.w;
  }
  const float bc = bias[c];
  const int nch = (n + 31) >> 5;
  for (int ch = blockIdx.x; ch < nch; ch += gridDim.x) {
    const int base = ch << 5;
    __syncthreads();  // protect LDS from previous iteration readers
    if (base + 32 <= n) {
      const float4* src = (const float4*)(feat + (size_t)base * C_IN);
      ((float4*)ldsF)[tid] = src[tid];
      ((float4*)ldsF)[tid + 256] = src[tid + 256];
    } else {
      for (int t = tid; t < 32 * C_IN; t += 256) {
        int p = base + (t >> 6);
        ldsF[t] = (p < n) ? feat[(size_t)p * C_IN + (t & 63)] : 0.f;
      }
    }
    if (tid < 32) ldsC[tid] = (base + tid < n) ? cluster[base + tid] : 0x80000000u;
    __syncthreads();
    for (int j = (wid >> 1); j < 32; j += 2) {
      if (base + j >= n) break;
      u32 cl = ldsC[j];
      if (cl & 0x80000000u) continue;  // multi-point cluster: handled in k8
      const float4* f4 = (const float4*)(ldsF + j * C_IN);
      float acc = bc;
#pragma unroll
      for (int q = 0; q < 16; q++) {
        float4 v = f4[q];
        acc = fmaf(v.x, wreg[4 * q], acc);
        acc = fmaf(v.y, wreg[4 * q + 1], acc);
        acc = fmaf(v.z, wreg[4 * q + 2], acc);
        acc = fmaf(v.w, wreg[4 * q + 3], acc);
      }
      out_feat[(size_t)cl * C_OUT + c] = acc;
    }
  }
}

// ---------- K7: counts, coord means, invalid-tail zeros ----------
__global__ void k7_finalize(const u64* __restrict__ pairs, const u32* __restrict__ segStart,
                            const u32* __restrict__ meta, const float* __restrict__ coord,
                            float* __restrict__ out_feat, float* __restrict__ out_coord,
                            float* __restrict__ out_grid, float* __restrict__ out_batch,
                            float* __restrict__ out_counts, int n) {
  int t = blockIdx.x * blockDim.x + threadIdx.x;
  if (t >= n) return;
  u32 numSeg = meta[0];
  if ((u32)t < numSeg) {
    u32 st = segStart[t], en = segStart[t + 1];
    u32 cnt = en - st;
    out_counts[t] = (float)cnt;
    float sx = 0.f, sy = 0.f, sz = 0.f;
    for (u32 e = st; e < en; e++) {
      u32 idx = (u32)(pairs[e] & 0xFFFFFFFFu);
      sx += coord[(size_t)idx * 3 + 0];
      sy += coord[(size_t)idx * 3 + 1];
      sz += coord[(size_t)idx * 3 + 2];
    }
    float fc = (float)cnt;
    out_coord[(size_t)t * 3 + 0] = sx / fc;
    out_coord[(size_t)t * 3 + 1] = sy / fc;
    out_coord[(size_t)t * 3 + 2] = sz / fc;
  } else {
    out_counts[t] = 0.f;
    out_batch[t] = 0.f;
    out_coord[(size_t)t * 3 + 0] = 0.f;
    out_coord[(size_t)t * 3 + 1] = 0.f;
    out_coord[(size_t)t * 3 + 2] = 0.f;
    out_grid[(size_t)t * 3 + 0] = 0.f;
    out_grid[(size_t)t * 3 + 1] = 0.f;
    out_grid[(size_t)t * 3 + 2] = 0.f;
    for (int c = 0; c < C_OUT; c++) out_feat[(size_t)t * C_OUT + c] = 0.f;
  }
}

// ---------- K8: multi-point clusters — parallel matmul + max (1 block/cluster) ----------
__global__ __launch_bounds__(128) void k8_multi(
    const u64* __restrict__ pairs, const u32* __restrict__ segStart,
    const u32* __restrict__ meta, const u32* __restrict__ multiList,
    const float* __restrict__ feat, const float* __restrict__ weight,
    const float* __restrict__ bias, float* __restrict__ out_feat) {
  __shared__ float ldsF[C_IN];
  const int c = threadIdx.x;  // one output channel per thread (128 threads)
  float wreg[C_IN];
  const float4* wrow = (const float4*)(weight + (size_t)c * C_IN);
#pragma unroll
  for (int q = 0; q < 16; q++) {
    float4 v = wrow[q];
    wreg[4 * q] = v.x; wreg[4 * q + 1] = v.y; wreg[4 * q + 2] = v.z; wreg[4 * q + 3] = v.w;
  }
  const float bc = bias[c];
  const u32 nm = meta[1];
  for (u32 m = blockIdx.x; m < nm; m += gridDim.x) {
    u32 seg = multiList[m];
    u32 st = segStart[seg], en = segStart[seg + 1];
    float mx = -3.4e38f;
    for (u32 e = st; e < en; e++) {
      u32 idx = (u32)(pairs[e] & 0xFFFFFFFFu);
      __syncthreads();
      if (c < 16) ((float4*)ldsF)[c] = ((const float4*)(feat + (size_t)idx * C_IN))[c];
      __syncthreads();
      float d = bc;
#pragma unroll
      for (int q = 0; q < 16; q++) {
        float4 v = ((const float4*)ldsF)[q];
        d = fmaf(v.x, wreg[4 * q], d);
        d = fmaf(v.y, wreg[4 * q + 1], d);
        d = fmaf(v.z, wreg[4 * q + 2], d);
        d = fmaf(v.w, wreg[4 * q + 3], d);
      }
      mx = fmaxf(mx, d);
    }
    out_feat[(size_t)seg * C_OUT + c] = mx;
  }
}

extern "C" void kernel_launch(void* const* d_in, const int* in_sizes, int n_in,
                              void* d_out, int out_size, void* d_ws, size_t ws_size,
                              hipStream_t stream) {
  const float* feat = (const float*)d_in[0];
  const float* coord = (const float*)d_in[1];
  const float* weight = (const float*)d_in[2];
  const float* bias = (const float*)d_in[3];
  const int* grid = (const int*)d_in[4];
  const int* batch = (const int*)d_in[5];
  const int* stride = (const int*)d_in[6];
  const int n = in_sizes[0] / C_IN;

  float* out_feat = (float*)d_out;
  float* out_coord = out_feat + (size_t)n * C_OUT;
  float* out_grid = out_coord + (size_t)n * 3;
  float* out_batch = out_grid + (size_t)n * 3;
  float* out_counts = out_batch + n;

  u32* W = (u32*)d_ws;
  u32* hist = W;                   // 65536
  u32* cursor = W + 65536;         // 65536
  u32* off = W + 131072;           // 65537
  u32* meta = W + 196864;          // [0]=numSeg [1]=numMulti
  u32* blockCnt = W + 196992;      // up to 2048
  u32* blockBase = W + 199040;     // up to 2048
  u32* multiList = W + 201088;     // up to 65536 entries
  u32* keys = W + 270336;          // n
  u32* cluster = keys + n;         // n
  u32* segStart = cluster + n;     // n+1
  size_t pe = 270336 + 3 * (size_t)n + 2;
  pe &= ~(size_t)1;                // 8-byte align for u64
  u64* pairs = (u64*)(W + pe);     // n

  hipMemsetAsync(hist, 0, NBUCK * sizeof(u32), stream);
  int nb = (n + 255) / 256;
  k1_keys<<<nb, 256, 0, stream>>>(grid, batch, stride, n, keys, hist);
  k2_scan<<<1, 1024, 0, stream>>>(hist, off, cursor);
  k3_scatter<<<nb, 256, 0, stream>>>(keys, cursor, pairs, n);
  k4_sort<<<NBUCK / 256, 256, 0, stream>>>(pairs, off);
  int nb5 = (n + 4095) / 4096;
  k5a_count<<<nb5, 256, 0, stream>>>(pairs, n, blockCnt);
  k5b_scanblocks<<<1, 256, 0, stream>>>(blockCnt, nb5, blockBase, meta, segStart, n);
  k5c_assign<<<nb5, 256, 0, stream>>>(pairs, n, blockBase, segStart, cluster, out_grid, out_batch,
                                      meta, multiList);
  k6_gemm<<<2048, 256, 0, stream>>>(feat, weight, bias, cluster, out_feat, n);
  k7_finalize<<<nb, 256, 0, stream>>>(pairs, segStart, meta, coord, out_feat, out_coord,
                                      out_grid, out_batch, out_counts, n);
  k8_multi<<<1024, 128, 0, stream>>>(pairs, segStart, meta, multiList, feat, weight, bias, out_feat);
}

// Round 3
// 332.601 us; speedup vs baseline: 2.2773x; 1.5822x over previous
//
#include <hip/hip_runtime.h>
#include <stdint.h>

#define C_IN 64
#define C_OUT 128
#define NBUCK 65536

typedef unsigned int u32;
typedef unsigned long long u64;

// ---------- K1: compute compressed keys + bucket histogram ----------
__global__ void k1_keys(const int* __restrict__ grid, const int* __restrict__ batch,
                        const int* __restrict__ stride, int n,
                        u32* __restrict__ keys, u32* __restrict__ hist) {
  int i = blockIdx.x * blockDim.x + threadIdx.x;
  if (i >= n) return;
  int s = stride[0];
  u32 gx = (u32)(grid[3 * i] / s);
  u32 gy = (u32)(grid[3 * i + 1] / s);
  u32 gz = (u32)(grid[3 * i + 2] / s);
  u32 b = (u32)batch[i];
  u32 key = (b << 30) | (gz << 20) | (gy << 10) | gx;
  keys[i] = key;
  atomicAdd(&hist[key >> 16], 1u);
}

// ---------- K2: exclusive scan of 65536 bucket counts (1 block) ----------
__global__ void k2_scan(const u32* __restrict__ hist, u32* __restrict__ off,
                        u32* __restrict__ cursor) {
  __shared__ u32 part[1024];
  int t = threadIdx.x;
  u32 s = 0;
  for (int k = 0; k < 64; k++) s += hist[t * 64 + k];
  part[t] = s;
  __syncthreads();
  for (int d = 1; d < 1024; d <<= 1) {
    u32 v = (t >= d) ? part[t - d] : 0u;
    __syncthreads();
    part[t] += v;
    __syncthreads();
  }
  u32 run = part[t] - s;  // exclusive base for this thread's 64 buckets
  for (int k = 0; k < 64; k++) {
    u32 h = hist[t * 64 + k];
    off[t * 64 + k] = run;
    cursor[t * 64 + k] = run;
    run += h;
  }
  if (t == 1023) off[NBUCK] = run;  // == n
}

// ---------- K3: scatter (key,idx) pairs into buckets ----------
__global__ void k3_scatter(const u32* __restrict__ keys, u32* __restrict__ cursor,
                           u64* __restrict__ pairs, int n) {
  int i = blockIdx.x * blockDim.x + threadIdx.x;
  if (i >= n) return;
  u32 key = keys[i];
  u32 pos = atomicAdd(&cursor[key >> 16], 1u);
  pairs[pos] = ((u64)key << 32) | (u32)i;
}

// ---------- K4: per-bucket rank sort, one WAVE per bucket ----------
// Full u64 (key,idx) compare => unique total order => deterministic output
// regardless of k3's atomic scatter order.
__global__ __launch_bounds__(256) void k4_sort(u64* __restrict__ pairs,
                                               const u32* __restrict__ off) {
  int wave = (blockIdx.x * blockDim.x + threadIdx.x) >> 6;
  int lane = threadIdx.x & 63;
  if (wave >= NBUCK) return;
  u32 lo = off[wave], hi = off[wave + 1];
  u32 k = hi - lo;
  if (k <= 1) return;
  if (k <= 64) {
    u64 v = (lane < (int)k) ? pairs[lo + lane] : ~0ull;
    int rank = 0;
    for (u32 j = 0; j < k; j++) {
      u64 o = __shfl(v, (int)j, 64);
      rank += (o < v) ? 1 : 0;
    }
    // all lane loads completed before any store (single-wave lockstep)
    if (lane < (int)k) pairs[lo + rank] = v;
  } else if (lane == 0) {  // cold fallback, statistically never taken
    for (u32 i = lo + 1; i < hi; i++) {
      u64 v = pairs[i];
      u32 j = i;
      while (j > lo && pairs[j - 1] > v) { pairs[j] = pairs[j - 1]; j--; }
      pairs[j] = v;
    }
  }
}

// ---------- K5a: per-block head counts (4096 positions/block) ----------
__global__ void k5a_count(const u64* __restrict__ pairs, int n, u32* __restrict__ blockCnt) {
  __shared__ u32 part[256];
  int tid = threadIdx.x;
  int p0 = blockIdx.x * 4096 + tid * 16;
  u32 cnt = 0;
  u32 prevkey = (p0 > 0 && p0 < n) ? (u32)(pairs[p0 - 1] >> 32) : 0u;
  for (int r = 0; r < 16; r++) {
    int p = p0 + r;
    if (p >= n) break;
    u32 k = (u32)(pairs[p] >> 32);
    cnt += (p == 0) || (k != prevkey);
    prevkey = k;
  }
  part[tid] = cnt;
  __syncthreads();
  for (int d = 128; d > 0; d >>= 1) {
    if (tid < d) part[tid] += part[tid + d];
    __syncthreads();
  }
  if (tid == 0) blockCnt[blockIdx.x] = part[0];
}

// ---------- K5b: scan block head counts (1 block, nb<=256) ----------
__global__ void k5b_scanblocks(const u32* __restrict__ blockCnt, int nb,
                               u32* __restrict__ blockBase, u32* __restrict__ meta,
                               u32* __restrict__ segStart, int n) {
  __shared__ u32 part[256];
  int t = threadIdx.x;
  u32 v = (t < nb) ? blockCnt[t] : 0u;
  part[t] = v;
  __syncthreads();
  for (int d = 1; d < 256; d <<= 1) {
    u32 x = (t >= d) ? part[t - d] : 0u;
    __syncthreads();
    part[t] += x;
    __syncthreads();
  }
  if (t < nb) blockBase[t] = part[t] - v;
  if (t == 254) meta[1] = 0u;  // reset multi-cluster counter (runs before k5c)
  if (t == 255) {
    u32 total = part[255];
    meta[0] = total;           // number of unique segments
    segStart[total] = (u32)n;  // sentinel
  }
}

// ---------- K5c: assign ranks, write cluster ids (+multi flag), seg starts, grid/batch ----------
__global__ void k5c_assign(const u64* __restrict__ pairs, int n,
                           const u32* __restrict__ blockBase,
                           u32* __restrict__ segStart, u32* __restrict__ cluster,
                           float* __restrict__ out_grid, float* __restrict__ out_batch,
                           u32* __restrict__ meta, u32* __restrict__ multiList) {
  __shared__ u32 part[256];
  int tid = threadIdx.x;
  int p0 = blockIdx.x * 4096 + tid * 16;
  u32 cnt = 0;
  u32 prevkey = (p0 > 0 && p0 < n) ? (u32)(pairs[p0 - 1] >> 32) : 0u;
  for (int r = 0; r < 16; r++) {
    int p = p0 + r;
    if (p >= n) break;
    u32 k = (u32)(pairs[p] >> 32);
    cnt += (p == 0) || (k != prevkey);
    prevkey = k;
  }
  part[tid] = cnt;
  __syncthreads();
  for (int d = 1; d < 256; d <<= 1) {
    u32 x = (tid >= d) ? part[tid - d] : 0u;
    __syncthreads();
    part[tid] += x;
    __syncthreads();
  }
  u32 heads = blockBase[blockIdx.x] + part[tid] - cnt;
  prevkey = (p0 > 0 && p0 < n) ? (u32)(pairs[p0 - 1] >> 32) : 0u;
  for (int r = 0; r < 16; r++) {
    int p = p0 + r;
    if (p >= n) break;
    u64 cur = pairs[p];
    u32 k = (u32)(cur >> 32);
    bool head = (p == 0) || (k != prevkey);
    bool next_eq = (p + 1 < n) && ((u32)(pairs[p + 1] >> 32) == k);
    if (head) {
      segStart[heads] = (u32)p;
      out_grid[(size_t)heads * 3 + 0] = (float)(k & 0x3FFu);
      out_grid[(size_t)heads * 3 + 1] = (float)((k >> 10) & 0x3FFu);
      out_grid[(size_t)heads * 3 + 2] = (float)((k >> 20) & 0x3FFu);
      out_batch[heads] = (float)(k >> 30);
      heads++;
      if (next_eq) {  // multi-point cluster: record seg id for k8
        u32 slot = atomicAdd(&meta[1], 1u);
        multiList[slot] = heads - 1;
      }
    }
    u32 seg = heads - 1;
    bool prev_eq = (p > 0) && (prevkey == k);
    u32 multi = (next_eq || prev_eq) ? 0x80000000u : 0u;
    cluster[(u32)(cur & 0xFFFFFFFFu)] = seg | multi;
    prevkey = k;
  }
}

// ---------- K6: fused GEMM + scatter store for singleton clusters ----------
__global__ __launch_bounds__(256) void k6_gemm(
    const float* __restrict__ feat, const float* __restrict__ weight,
    const float* __restrict__ bias, const u32* __restrict__ cluster,
    float* __restrict__ out_feat, int n) {
  __shared__ float ldsF[32 * C_IN];
  __shared__ u32 ldsC[32];
  const int tid = threadIdx.x;
  const int lane = tid & 63;
  const int wid = tid >> 6;
  const int h = wid & 1;
  const int c = h * 64 + lane;  // output channel owned by this thread
  float wreg[C_IN];
  const float4* wrow = (const float4*)(weight + (size_t)c * C_IN);
#pragma unroll
  for (int q = 0; q < 16; q++) {
    float4 v = wrow[q];
    wreg[4 * q] = v.x; wreg[4 * q + 1] = v.y; wreg[4 * q + 2] = v.z; wreg[4 * q + 3] = v.w;
  }
  const float bc = bias[c];
  const int nch = (n + 31) >> 5;
  for (int ch = blockIdx.x; ch < nch; ch += gridDim.x) {
    const int base = ch << 5;
    __syncthreads();  // protect LDS from previous iteration readers
    if (base + 32 <= n) {
      const float4* src = (const float4*)(feat + (size_t)base * C_IN);
      ((float4*)ldsF)[tid] = src[tid];
      ((float4*)ldsF)[tid + 256] = src[tid + 256];
    } else {
      for (int t = tid; t < 32 * C_IN; t += 256) {
        int p = base + (t >> 6);
        ldsF[t] = (p < n) ? feat[(size_t)p * C_IN + (t & 63)] : 0.f;
      }
    }
    if (tid < 32) ldsC[tid] = (base + tid < n) ? cluster[base + tid] : 0x80000000u;
    __syncthreads();
    for (int j = (wid >> 1); j < 32; j += 2) {
      if (base + j >= n) break;
      u32 cl = ldsC[j];
      if (cl & 0x80000000u) continue;  // multi-point cluster: handled in k8
      const float4* f4 = (const float4*)(ldsF + j * C_IN);
      float acc = bc;
#pragma unroll
      for (int q = 0; q < 16; q++) {
        float4 v = f4[q];
        acc = fmaf(v.x, wreg[4 * q], acc);
        acc = fmaf(v.y, wreg[4 * q + 1], acc);
        acc = fmaf(v.z, wreg[4 * q + 2], acc);
        acc = fmaf(v.w, wreg[4 * q + 3], acc);
      }
      out_feat[(size_t)cl * C_OUT + c] = acc;
    }
  }
}

// ---------- K7: counts, coord means, invalid-tail zeros ----------
__global__ void k7_finalize(const u64* __restrict__ pairs, const u32* __restrict__ segStart,
                            const u32* __restrict__ meta, const float* __restrict__ coord,
                            float* __restrict__ out_feat, float* __restrict__ out_coord,
                            float* __restrict__ out_grid, float* __restrict__ out_batch,
                            float* __restrict__ out_counts, int n) {
  int t = blockIdx.x * blockDim.x + threadIdx.x;
  if (t >= n) return;
  u32 numSeg = meta[0];
  if ((u32)t < numSeg) {
    u32 st = segStart[t], en = segStart[t + 1];
    u32 cnt = en - st;
    out_counts[t] = (float)cnt;
    float sx = 0.f, sy = 0.f, sz = 0.f;
    for (u32 e = st; e < en; e++) {
      u32 idx = (u32)(pairs[e] & 0xFFFFFFFFu);
      sx += coord[(size_t)idx * 3 + 0];
      sy += coord[(size_t)idx * 3 + 1];
      sz += coord[(size_t)idx * 3 + 2];
    }
    float fc = (float)cnt;
    out_coord[(size_t)t * 3 + 0] = sx / fc;
    out_coord[(size_t)t * 3 + 1] = sy / fc;
    out_coord[(size_t)t * 3 + 2] = sz / fc;
  } else {
    out_counts[t] = 0.f;
    out_batch[t] = 0.f;
    out_coord[(size_t)t * 3 + 0] = 0.f;
    out_coord[(size_t)t * 3 + 1] = 0.f;
    out_coord[(size_t)t * 3 + 2] = 0.f;
    out_grid[(size_t)t * 3 + 0] = 0.f;
    out_grid[(size_t)t * 3 + 1] = 0.f;
    out_grid[(size_t)t * 3 + 2] = 0.f;
    for (int c = 0; c < C_OUT; c++) out_feat[(size_t)t * C_OUT + c] = 0.f;
  }
}

// ---------- K8: multi-point clusters — parallel matmul + max (1 block/cluster) ----------
__global__ __launch_bounds__(128) void k8_multi(
    const u64* __restrict__ pairs, const u32* __restrict__ segStart,
    const u32* __restrict__ meta, const u32* __restrict__ multiList,
    const float* __restrict__ feat, const float* __restrict__ weight,
    const float* __restrict__ bias, float* __restrict__ out_feat) {
  __shared__ float ldsF[C_IN];
  const int c = threadIdx.x;  // one output channel per thread (128 threads)
  float wreg[C_IN];
  const float4* wrow = (const float4*)(weight + (size_t)c * C_IN);
#pragma unroll
  for (int q = 0; q < 16; q++) {
    float4 v = wrow[q];
    wreg[4 * q] = v.x; wreg[4 * q + 1] = v.y; wreg[4 * q + 2] = v.z; wreg[4 * q + 3] = v.w;
  }
  const float bc = bias[c];
  const u32 nm = meta[1];
  for (u32 m = blockIdx.x; m < nm; m += gridDim.x) {
    u32 seg = multiList[m];
    u32 st = segStart[seg], en = segStart[seg + 1];
    float mx = -3.4e38f;
    for (u32 e = st; e < en; e++) {
      u32 idx = (u32)(pairs[e] & 0xFFFFFFFFu);
      __syncthreads();
      if (c < 16) ((float4*)ldsF)[c] = ((const float4*)(feat + (size_t)idx * C_IN))[c];
      __syncthreads();
      float d = bc;
#pragma unroll
      for (int q = 0; q < 16; q++) {
        float4 v = ((const float4*)ldsF)[q];
        d = fmaf(v.x, wreg[4 * q], d);
        d = fmaf(v.y, wreg[4 * q + 1], d);
        d = fmaf(v.z, wreg[4 * q + 2], d);
        d = fmaf(v.w, wreg[4 * q + 3], d);
      }
      mx = fmaxf(mx, d);
    }
    out_feat[(size_t)seg * C_OUT + c] = mx;
  }
}

extern "C" void kernel_launch(void* const* d_in, const int* in_sizes, int n_in,
                              void* d_out, int out_size, void* d_ws, size_t ws_size,
                              hipStream_t stream) {
  const float* feat = (const float*)d_in[0];
  const float* coord = (const float*)d_in[1];
  const float* weight = (const float*)d_in[2];
  const float* bias = (const float*)d_in[3];
  const int* grid = (const int*)d_in[4];
  const int* batch = (const int*)d_in[5];
  const int* stride = (const int*)d_in[6];
  const int n = in_sizes[0] / C_IN;

  float* out_feat = (float*)d_out;
  float* out_coord = out_feat + (size_t)n * C_OUT;
  float* out_grid = out_coord + (size_t)n * 3;
  float* out_batch = out_grid + (size_t)n * 3;
  float* out_counts = out_batch + n;

  u32* W = (u32*)d_ws;
  u32* hist = W;                   // 65536
  u32* cursor = W + 65536;         // 65536
  u32* off = W + 131072;           // 65537
  u32* meta = W + 196864;          // [0]=numSeg [1]=numMulti
  u32* blockCnt = W + 196992;      // up to 2048
  u32* blockBase = W + 199040;     // up to 2048
  u32* multiList = W + 201088;     // up to 65536 entries
  u32* keys = W + 270336;          // n
  u32* cluster = keys + n;         // n
  u32* segStart = cluster + n;     // n+1
  size_t pe = 270336 + 3 * (size_t)n + 2;
  pe &= ~(size_t)1;                // 8-byte align for u64
  u64* pairs = (u64*)(W + pe);     // n

  hipMemsetAsync(hist, 0, NBUCK * sizeof(u32), stream);
  int nb = (n + 255) / 256;
  k1_keys<<<nb, 256, 0, stream>>>(grid, batch, stride, n, keys, hist);
  k2_scan<<<1, 1024, 0, stream>>>(hist, off, cursor);
  k3_scatter<<<nb, 256, 0, stream>>>(keys, cursor, pairs, n);
  k4_sort<<<NBUCK / 4, 256, 0, stream>>>(pairs, off);  // one wave per bucket
  int nb5 = (n + 4095) / 4096;
  k5a_count<<<nb5, 256, 0, stream>>>(pairs, n, blockCnt);
  k5b_scanblocks<<<1, 256, 0, stream>>>(blockCnt, nb5, blockBase, meta, segStart, n);
  k5c_assign<<<nb5, 256, 0, stream>>>(pairs, n, blockBase, segStart, cluster, out_grid, out_batch,
                                      meta, multiList);
  k6_gemm<<<2048, 256, 0, stream>>>(feat, weight, bias, cluster, out_feat, n);
  k7_finalize<<<nb, 256, 0, stream>>>(pairs, segStart, meta, coord, out_feat, out_coord,
                                      out_grid, out_batch, out_counts, n);
  k8_multi<<<1024, 128, 0, stream>>>(pairs, segStart, meta, multiList, feat, weight, bias, out_feat);
}